// Round 3
// baseline (713.776 us; speedup 1.0000x reference)
//
#include <hip/hip_runtime.h>

// Swin-V2 shifted-window attention, fp32 in/out, MI355X gfx950.
// R7 = R6 with the nontemporal-load type fixed (ext_vector f32x4, not HIP float4).
//  - non-temporal x loads / out stores: streaming traffic (read-once/write-once)
//    no longer evicts the 512KB fragment-major weight buffer from L2 (R5 showed
//    weight re-fetch = +234MB HBM when L2 thrashes).
//  - V kept in registers, B-fragments built with the R5-verified quad-shuffle:
//    drops the 16KB vT LDS buffer (80->64 KB LDS) and its scattered writes.
//  - cpb + prep_w merged into one dispatch (launch-gap savings).
// MFMA 16x16x32 bf16 layouts (HW-verified): A/B[row=lane&15][k=(lane>>4)*8+j],
// C/D[col=lane&15][row=(lane>>4)*4+reg].
// Fragment-major storage of a [T x F] operand tile: addr(t,f) = ((f>>3)*64 + t)*8 + (f&7).

typedef __bf16 bf16_t;
typedef __attribute__((ext_vector_type(8))) __bf16 bf16x8;
typedef __attribute__((ext_vector_type(4))) float f32x4;

__device__ __forceinline__ f32x4 mfma16(bf16x8 a, bf16x8 b, f32x4 c) {
  return __builtin_amdgcn_mfma_f32_16x16x32_bf16(a, b, c, 0, 0, 0);
}

__device__ __forceinline__ bf16x8 cvt8(const float* f) {
  f32x4 a = *(const f32x4*)f;
  f32x4 b = *(const f32x4*)(f + 4);
  bf16x8 r;
  r[0] = (bf16_t)a.x; r[1] = (bf16_t)a.y; r[2] = (bf16_t)a.z; r[3] = (bf16_t)a.w;
  r[4] = (bf16_t)b.x; r[5] = (bf16_t)b.y; r[6] = (bf16_t)b.z; r[7] = (bf16_t)b.w;
  return r;
}

// non-temporal variant: x is read exactly once per dispatch — don't cache it.
__device__ __forceinline__ bf16x8 cvt8nt(const float* f) {
  f32x4 a = __builtin_nontemporal_load((const f32x4*)f);
  f32x4 b = __builtin_nontemporal_load((const f32x4*)f + 1);
  bf16x8 r;
  r[0] = (bf16_t)a.x; r[1] = (bf16_t)a.y; r[2] = (bf16_t)a.z; r[3] = (bf16_t)a.w;
  r[4] = (bf16_t)b.x; r[5] = (bf16_t)b.y; r[6] = (bf16_t)b.z; r[7] = (bf16_t)b.w;
  return r;
}

__device__ __forceinline__ uint32_t pack2(float a, float b) {
  union { bf16_t h[2]; uint32_t u; } t;
  t.h[0] = (bf16_t)a; t.h[1] = (bf16_t)b;
  return t.u;
}

__device__ __forceinline__ float clampv(float v) {
  return fminf(fmaxf(v, -1.0e4f), 1.0e4f);
}

// Build one B-fragment (16 dims x 32 contraction-keys) from C-layout register data.
// Source lane (qs,l16) word r-pair of block mt holds V[t=mt*16+qs*4+{r}][d=nd*16+l16].
// Dest lane (Q,l16) word w: keys base+Q*8+2w,+1 -> src lane sA=(Q&1)*32+l16 (w=0,1)
// / sB=sA+16 (w=2,3), lo word for even w, hi for odd; block mt parity by miHi=(Q>=2).
// Verified numerically in the R5 run (passed, absmax 0.015625).
__device__ __forceinline__ bf16x8 quadshuf(uint32_t lo0, uint32_t hi0,
                                           uint32_t lo1, uint32_t hi1,
                                           int sA, int sB, bool miHi) {
  int a0 = __shfl((int)lo0, sA), a1 = __shfl((int)lo1, sA);
  int b0 = __shfl((int)hi0, sA), b1 = __shfl((int)hi1, sA);
  int c0 = __shfl((int)lo0, sB), c1 = __shfl((int)lo1, sB);
  int d0 = __shfl((int)hi0, sB), d1 = __shfl((int)hi1, sB);
  union { uint32_t w[4]; bf16x8 v; } f;
  f.w[0] = (uint32_t)(miHi ? a1 : a0);
  f.w[1] = (uint32_t)(miHi ? b1 : b0);
  f.w[2] = (uint32_t)(miHi ? c1 : c0);
  f.w[3] = (uint32_t)(miHi ? d1 : d0);
  return f.v;
}

// ---------------- merged prep: CPB-MLP bias table + fragment-major weights ----------
// blocks 0..127  : prep_w role (if doW) — 256 thr, coalesced 32B/lane reads.
// blocks 128..352: cpb role — first wave only.
__global__ void prep_all(const float* __restrict__ Wq, const float* __restrict__ Wk,
                         const float* __restrict__ Wv, const float* __restrict__ Wo,
                         const float* __restrict__ w1, const float* __restrict__ b1,
                         const float* __restrict__ w2, bf16_t* __restrict__ wf,
                         float* __restrict__ tab, int doW) {
  if (blockIdx.x < 128) {
    if (!doW) return;
    int gid = blockIdx.x * 256 + threadIdx.x;  // 4 mats x 256 rows x 32 col-blocks
    int mat = gid >> 13, rem = gid & 8191;
    int row = rem >> 5, col = (rem & 31) << 3;
    const float* W = (mat == 0) ? Wq : (mat == 1) ? Wk : (mat == 2) ? Wv : Wo;
    bf16x8 v = cvt8(W + row * 256 + col);
    int rblk = row >> 4, kk = col >> 5, qd = (col >> 3) & 3, lr = row & 15;
    size_t dst = ((size_t)(((mat * 16 + rblk) * 8 + kk) * 64 + qd * 16 + lr)) * 8;
    *(bf16x8*)(wf + dst) = v;
    return;
  }
  if (threadIdx.x >= 64) return;
  int e = blockIdx.x - 128;  // 0..224
  int t = threadIdx.x;       // 0..63
  int a = e / 15, bcol = e % 15;
  float t0 = ((float)(a - 7) / 7.0f) * 8.0f;
  float t1 = ((float)(bcol - 7) / 7.0f) * 8.0f;
  float s0 = (t0 > 0.f) ? 1.f : ((t0 < 0.f) ? -1.f : 0.f);
  float s1 = (t1 > 0.f) ? 1.f : ((t1 < 0.f) ? -1.f : 0.f);
  t0 = s0 * log2f(fabsf(t0) + 1.f) * (1.0f / 3.0f);  // /log2(8)
  t1 = s1 * log2f(fabsf(t1) + 1.f) * (1.0f / 3.0f);
  float accv[8];
#pragma unroll
  for (int i = 0; i < 8; ++i) accv[i] = 0.f;
#pragma unroll
  for (int i = 0; i < 8; ++i) {
    int j = t + 64 * i;
    float hd = fmaxf(t0 * w1[2 * j] + t1 * w1[2 * j + 1] + b1[j], 0.f);
#pragma unroll
    for (int hh = 0; hh < 8; ++hh) accv[hh] += hd * w2[hh * 512 + j];
  }
#pragma unroll
  for (int hh = 0; hh < 8; ++hh) {
    float v = accv[hh];
    v += __shfl_xor(v, 1);  v += __shfl_xor(v, 2);  v += __shfl_xor(v, 4);
    v += __shfl_xor(v, 8);  v += __shfl_xor(v, 16); v += __shfl_xor(v, 32);
    accv[hh] = v;
  }
  if (t < 8) tab[e * 8 + t] = 16.f / (1.f + __expf(-accv[t]));
}

// ---------------- fused per-window attention ---------------------------------------
template <bool PREP>
__global__ void __launch_bounds__(256, 2) swin_fused(
    const float* __restrict__ x,
    const float* __restrict__ Wq, const float* __restrict__ bq,
    const float* __restrict__ Wk, const float* __restrict__ bk,
    const float* __restrict__ Wv, const float* __restrict__ bv,
    const float* __restrict__ Wo, const float* __restrict__ bo,
    const float* __restrict__ ls, const float* __restrict__ btab,
    const bf16_t* __restrict__ wf, float* __restrict__ out) {
  __shared__ __align__(16) bf16_t xsf[16384];      // 32 KB: x frags; later y frags
  __shared__ __align__(16) bf16_t scr[4 * 4096];   // 32 KB: per-wave q|k (P overlays)
  const int tid = threadIdx.x;
  const int lane = tid & 63, wave = tid >> 6, quad = lane >> 4, l16 = lane & 15;
  const int win = blockIdx.x, bb = win >> 6, wh = (win >> 3) & 7, ww = win & 7;
  const f32x4 fz = {0.f, 0.f, 0.f, 0.f};
  const int sA = ((quad & 1) << 5) | l16;  // quadshuf source lanes
  const int sB = sA + 16;
  const bool miHi = (lane & 32) != 0;

  // ---- Phase 0: stage shifted x-window -> xsf (fragment-major bf16), nt loads ----
  {
    int t = tid >> 2, fq = tid & 3;
    int gh = (wh * 8 + (t >> 3) + 4) & 63;
    int gw = (ww * 8 + (t & 7) + 4) & 63;
    const float* xp = x + (size_t)((bb * 64 + gh) * 64 + gw) * 256 + fq * 64;
    bf16_t* dst = xsf + t * 8;
#pragma unroll
    for (int fc = 0; fc < 8; ++fc)
      *(bf16x8*)(dst + (fq * 8 + fc) * 512) = cvt8nt(xp + fc * 8);
  }
  __syncthreads();

  bf16_t* qf = scr + wave * 4096;  // q frags [2048 el]
  bf16_t* kf = qf + 2048;          // k frags [2048 el]
  bf16_t* pf = qf;                 // P frags [4096 el] overlay q|k (dead after QK^T)

  // key-region ids for shifted-window mask
  int regm[4];
#pragma unroll
  for (int ni = 0; ni < 4; ++ni) {
    int m = ni * 16 + l16;
    int rr = (wh == 7) ? (((m >> 3) < 4) ? 1 : 2) : 0;
    int cc = (ww == 7) ? (((m & 7) < 4) ? 1 : 2) : 0;
    regm[ni] = rr * 3 + cc;
  }

  f32x4 oh[2][4][2];  // attention outputs for both head passes (C-layout)

  for (int hp = 0; hp < 2; ++hp) {
    const int h = hp * 4 + wave;

    // ---- Phase A: QKV projection (A: LDS frags; B: frag-major global weights) ----
    f32x4 acc[4][6];
#pragma unroll
    for (int mi = 0; mi < 4; ++mi)
#pragma unroll
      for (int ni = 0; ni < 6; ++ni) acc[mi][ni] = fz;

#pragma unroll
    for (int kk = 0; kk < 8; ++kk) {
      bf16x8 af[4];
      const bf16_t* xb = xsf + ((kk * 4 + quad) * 64 + l16) * 8;
#pragma unroll
      for (int mi = 0; mi < 4; ++mi) af[mi] = *(const bf16x8*)(xb + mi * 128);
      bf16x8 bw[6];
      if (PREP) {
#pragma unroll
        for (int m3 = 0; m3 < 3; ++m3)
#pragma unroll
          for (int ni = 0; ni < 2; ++ni)
            bw[m3 * 2 + ni] = *(const bf16x8*)(
                wf + (size_t)(((m3 * 16 + h * 2 + ni) * 8 + kk) * 64 + lane) * 8);
      } else {
        const float* Wm[3] = {Wq, Wk, Wv};
#pragma unroll
        for (int m3 = 0; m3 < 3; ++m3)
#pragma unroll
          for (int ni = 0; ni < 2; ++ni)
            bw[m3 * 2 + ni] =
                cvt8(Wm[m3] + (h * 32 + ni * 16 + l16) * 256 + kk * 32 + quad * 8);
      }
#pragma unroll
      for (int ni = 0; ni < 6; ++ni)
#pragma unroll
        for (int mi = 0; mi < 4; ++mi) acc[mi][ni] = mfma16(af[mi], bw[ni], acc[mi][ni]);
    }

    // hp1: all waves are past their last xsf read once everyone reaches here.
    if (hp == 1) {
      __syncthreads();
      // write hp0's O into y frags (overlay xsf): f = wave*32 + d
#pragma unroll
      for (int mi = 0; mi < 4; ++mi)
#pragma unroll
        for (int r = 0; r < 4; ++r) {
          int row = mi * 16 + quad * 4 + r;
          xsf[(wave * 4 + (l16 >> 3)) * 512 + row * 8 + (l16 & 7)]     = (bf16_t)oh[0][mi][0][r];
          xsf[(wave * 4 + 2 + (l16 >> 3)) * 512 + row * 8 + (l16 & 7)] = (bf16_t)oh[0][mi][1][r];
        }
    }

    const float bq0 = bq[h * 32 + l16],      bq1 = bq[h * 32 + 16 + l16];
    const float bk0 = bk[h * 32 + l16],      bk1 = bk[h * 32 + 16 + l16];
    const float bv0 = bv[h * 32 + l16],      bv1 = bv[h * 32 + 16 + l16];

    // ---- Phase B: bias + cosine-normalize; stage q,k frags; V -> registers ----
#pragma unroll
    for (int mi = 0; mi < 4; ++mi)
#pragma unroll
      for (int r = 0; r < 4; ++r) {
        float q0 = acc[mi][0][r] + bq0, q1 = acc[mi][1][r] + bq1;
        float k0 = acc[mi][2][r] + bk0, k1 = acc[mi][3][r] + bk1;
        float sq = q0 * q0 + q1 * q1;
        sq += __shfl_xor(sq, 1); sq += __shfl_xor(sq, 2);
        sq += __shfl_xor(sq, 4); sq += __shfl_xor(sq, 8);
        float rq = 1.f / fmaxf(sqrtf(sq), 1e-12f);
        float sk = k0 * k0 + k1 * k1;
        sk += __shfl_xor(sk, 1); sk += __shfl_xor(sk, 2);
        sk += __shfl_xor(sk, 4); sk += __shfl_xor(sk, 8);
        float rk = 1.f / fmaxf(sqrtf(sk), 1e-12f);
        int row = mi * 16 + quad * 4 + r;
        int qa0 = (l16 >> 3) * 512 + row * 8 + (l16 & 7);
        qf[qa0]              = (bf16_t)(q0 * rq);
        qf[qa0 + 2 * 512]    = (bf16_t)(q1 * rq);
        kf[qa0]              = (bf16_t)(k0 * rk);
        kf[qa0 + 2 * 512]    = (bf16_t)(k1 * rk);
      }
    // V stays in registers: vlo/vhi[mt][nd] pack V[t=mt*16+quad*4+{0,1}/{2,3}][d=nd*16+l16]
    uint32_t vlo[4][2], vhi[4][2];
#pragma unroll
    for (int mt = 0; mt < 4; ++mt)
#pragma unroll
      for (int nd = 0; nd < 2; ++nd) {
        const float bvb = nd ? bv1 : bv0;
        vlo[mt][nd] = pack2(acc[mt][4 + nd][0] + bvb, acc[mt][4 + nd][1] + bvb);
        vhi[mt][nd] = pack2(acc[mt][4 + nd][2] + bvb, acc[mt][4 + nd][3] + bvb);
      }

    // ---- Phase C: S = qn @ kn^T (conflict-free b128 frag reads) ----
    f32x4 s[4][4];
    {
      bf16x8 qa[4], kb[4];
#pragma unroll
      for (int mi = 0; mi < 4; ++mi)
        qa[mi] = *(const bf16x8*)(qf + (quad * 64 + mi * 16 + l16) * 8);
#pragma unroll
      for (int ni = 0; ni < 4; ++ni)
        kb[ni] = *(const bf16x8*)(kf + (quad * 64 + ni * 16 + l16) * 8);
#pragma unroll
      for (int mi = 0; mi < 4; ++mi)
#pragma unroll
        for (int ni = 0; ni < 4; ++ni) s[mi][ni] = mfma16(qa[mi], kb[ni], fz);
    }

    const float scale = __expf(fminf(ls[h], 4.6051702f));  // exp(min(ls, ln 100))

    // ---- scale + CPB bias + shifted-window mask ----
#pragma unroll
    for (int mi = 0; mi < 4; ++mi)
#pragma unroll
      for (int r = 0; r < 4; ++r) {
        int n = mi * 16 + quad * 4 + r;  // query token
        int nrr = (wh == 7) ? (((n >> 3) < 4) ? 1 : 2) : 0;
        int ncc = (ww == 7) ? (((n & 7) < 4) ? 1 : 2) : 0;
        int regn = nrr * 3 + ncc;
#pragma unroll
        for (int ni = 0; ni < 4; ++ni) {
          int m = ni * 16 + l16;  // key token
          int idx = ((n >> 3) - (m >> 3) + 7) * 15 + ((n & 7) - (m & 7) + 7);
          float v = s[mi][ni][r] * scale + btab[idx * 8 + h];
          if (regn != regm[ni]) v -= 100.f;
          s[mi][ni][r] = v;
        }
      }

    // ---- Phase D: softmax rows -> P frags (overlay q|k, wave-private) ----
#pragma unroll
    for (int mi = 0; mi < 4; ++mi)
#pragma unroll
      for (int r = 0; r < 4; ++r) {
        float mx = fmaxf(fmaxf(s[mi][0][r], s[mi][1][r]), fmaxf(s[mi][2][r], s[mi][3][r]));
        mx = fmaxf(mx, __shfl_xor(mx, 1)); mx = fmaxf(mx, __shfl_xor(mx, 2));
        mx = fmaxf(mx, __shfl_xor(mx, 4)); mx = fmaxf(mx, __shfl_xor(mx, 8));
        float sum = 0.f;
#pragma unroll
        for (int ni = 0; ni < 4; ++ni) {
          float p = __expf(s[mi][ni][r] - mx);
          s[mi][ni][r] = p;
          sum += p;
        }
        sum += __shfl_xor(sum, 1); sum += __shfl_xor(sum, 2);
        sum += __shfl_xor(sum, 4); sum += __shfl_xor(sum, 8);
        float inv = 1.f / sum;
        int row = mi * 16 + quad * 4 + r;
#pragma unroll
        for (int ni = 0; ni < 4; ++ni) {
          int m = ni * 16 + l16;  // key token
          int pa = ((row >> 4) * 2 + (m >> 5)) * 512 +
                   (((m >> 3) & 3) * 16 + (row & 15)) * 8 + (m & 7);
          pf[pa] = (bf16_t)(s[mi][ni][r] * inv);
        }
      }

    // ---- Phase E: O = P @ V (P from LDS frags; V B-frags via quadshuf) ----
#pragma unroll
    for (int mi = 0; mi < 4; ++mi) { oh[hp][mi][0] = fz; oh[hp][mi][1] = fz; }
#pragma unroll
    for (int k2 = 0; k2 < 2; ++k2) {
      bf16x8 pa[4];
#pragma unroll
      for (int mi = 0; mi < 4; ++mi)
        pa[mi] = *(const bf16x8*)(pf + ((mi * 2 + k2) * 64 + lane) * 8);
      bf16x8 vfr[2];
#pragma unroll
      for (int nd = 0; nd < 2; ++nd)
        vfr[nd] = quadshuf(vlo[2 * k2][nd], vhi[2 * k2][nd],
                           vlo[2 * k2 + 1][nd], vhi[2 * k2 + 1][nd], sA, sB, miHi);
#pragma unroll
      for (int n2 = 0; n2 < 2; ++n2)
#pragma unroll
        for (int mi = 0; mi < 4; ++mi) oh[hp][mi][n2] = mfma16(pa[mi], vfr[n2], oh[hp][mi][n2]);
    }
  }

  // write hp1's O into y frags: f = (4+wave)*32 + d
#pragma unroll
  for (int mi = 0; mi < 4; ++mi)
#pragma unroll
    for (int r = 0; r < 4; ++r) {
      int row = mi * 16 + quad * 4 + r;
      int h1 = 4 + wave;
      xsf[(h1 * 4 + (l16 >> 3)) * 512 + row * 8 + (l16 & 7)]     = (bf16_t)oh[1][mi][0][r];
      xsf[(h1 * 4 + 2 + (l16 >> 3)) * 512 + row * 8 + (l16 & 7)] = (bf16_t)oh[1][mi][1][r];
    }
  __syncthreads();

  // ---- Phase F: out = y @ Wo^T + bo, direct unshift-scatter store (nt) ----
  f32x4 a2[4][4];
#pragma unroll
  for (int mi = 0; mi < 4; ++mi)
#pragma unroll
    for (int ni = 0; ni < 4; ++ni) a2[mi][ni] = fz;

#pragma unroll
  for (int kk = 0; kk < 8; ++kk) {
    bf16x8 af[4];
    const bf16_t* yb = xsf + ((kk * 4 + quad) * 64 + l16) * 8;
#pragma unroll
    for (int mi = 0; mi < 4; ++mi) af[mi] = *(const bf16x8*)(yb + mi * 128);
#pragma unroll
    for (int ni = 0; ni < 4; ++ni) {
      bf16x8 bw;
      if (PREP)
        bw = *(const bf16x8*)(wf + (size_t)(((48 + wave * 4 + ni) * 8 + kk) * 64 + lane) * 8);
      else
        bw = cvt8(Wo + (wave * 64 + ni * 16 + l16) * 256 + kk * 32 + quad * 8);
#pragma unroll
      for (int mi = 0; mi < 4; ++mi) a2[mi][ni] = mfma16(af[mi], bw, a2[mi][ni]);
    }
  }

  float bor[4];
#pragma unroll
  for (int ni = 0; ni < 4; ++ni) bor[ni] = bo[wave * 64 + ni * 16 + l16];
#pragma unroll
  for (int mi = 0; mi < 4; ++mi)
#pragma unroll
    for (int r = 0; r < 4; ++r) {
      int row = mi * 16 + quad * 4 + r;
      int gh = (wh * 8 + (row >> 3) + 4) & 63;
      int gw = (ww * 8 + (row & 7) + 4) & 63;
      float* op = out + (size_t)((bb * 64 + gh) * 64 + gw) * 256 + wave * 64 + l16;
#pragma unroll
      for (int ni = 0; ni < 4; ++ni)
        __builtin_nontemporal_store(clampv(a2[mi][ni][r] + bor[ni]), op + ni * 16);
    }
}

extern "C" void kernel_launch(void* const* d_in, const int* in_sizes, int n_in,
                              void* d_out, int out_size, void* d_ws, size_t ws_size,
                              hipStream_t stream) {
  const float* x  = (const float*)d_in[0];
  const float* Wq = (const float*)d_in[1];
  const float* bq = (const float*)d_in[2];
  const float* Wk = (const float*)d_in[3];
  const float* bk = (const float*)d_in[4];
  const float* Wv = (const float*)d_in[5];
  const float* bv = (const float*)d_in[6];
  const float* Wo = (const float*)d_in[7];
  const float* bo = (const float*)d_in[8];
  const float* ls = (const float*)d_in[9];
  const float* w1 = (const float*)d_in[10];
  const float* b1 = (const float*)d_in[11];
  const float* w2 = (const float*)d_in[12];

  float* tab = (float*)d_ws;                           // 1800 floats (7.2 KB)
  bf16_t* wfrag = (bf16_t*)((char*)d_ws + 7680);       // 512 KB fragment-major weights
  const bool prep = ws_size >= (size_t)(7680 + 524288);  // constant across calls

  hipLaunchKernelGGL(prep_all, dim3(353), dim3(256), 0, stream,
                     Wq, Wk, Wv, Wo, w1, b1, w2, wfrag, tab, prep ? 1 : 0);
  if (prep) {
    hipLaunchKernelGGL((swin_fused<true>), dim3(2048), dim3(256), 0, stream,
                       x, Wq, bq, Wk, bk, Wv, bv, Wo, bo, ls, tab, wfrag, (float*)d_out);
  } else {
    hipLaunchKernelGGL((swin_fused<false>), dim3(2048), dim3(256), 0, stream,
                       x, Wq, bq, Wk, bk, Wv, bv, Wo, bo, ls, tab, wfrag, (float*)d_out);
  }
}

// Round 4
// 451.773 us; speedup vs baseline: 1.5799x; 1.5799x over previous
//
#include <hip/hip_runtime.h>

// Swin-V2 shifted-window attention, fp32 in/out, MI355X gfx950.
// R8: 512-thread blocks, 8 waves, ONE head per wave (hp loop removed), with the
// R5-verified all-register attention core (swapped-operand q/k projection ->
// quad-shuffle fragments; no per-wave LDS staging at all). LDS = x/y fragment
// buffer only, padded to 64 KB to PIN 2 blocks/CU: same streaming pressure per
// XCD as the measured-best R4 (FETCH ~207MB), but 4 waves/SIMD (2x R4) and half
// the per-wave serial path. nt hints reverted (R7: +79MB FETCH, slower).
// MFMA 16x16x32 bf16 layouts (HW-verified): A/B[row=lane&15][k=(lane>>4)*8+j],
// C/D[col=lane&15 (B.n)][row=(lane>>4)*4+reg (A.m)].
// Fragment-major storage of a [T x F] tile: addr(t,f) = ((f>>3)*64 + t)*8 + (f&7).

typedef __bf16 bf16_t;
typedef __attribute__((ext_vector_type(8))) __bf16 bf16x8;
typedef __attribute__((ext_vector_type(4))) float f32x4;

__device__ __forceinline__ f32x4 mfma16(bf16x8 a, bf16x8 b, f32x4 c) {
  return __builtin_amdgcn_mfma_f32_16x16x32_bf16(a, b, c, 0, 0, 0);
}

__device__ __forceinline__ bf16x8 cvt8(const float* f) {
  f32x4 a = *(const f32x4*)f;
  f32x4 b = *(const f32x4*)(f + 4);
  bf16x8 r;
  r[0] = (bf16_t)a.x; r[1] = (bf16_t)a.y; r[2] = (bf16_t)a.z; r[3] = (bf16_t)a.w;
  r[4] = (bf16_t)b.x; r[5] = (bf16_t)b.y; r[6] = (bf16_t)b.z; r[7] = (bf16_t)b.w;
  return r;
}

__device__ __forceinline__ uint32_t pack2(float a, float b) {
  union { bf16_t h[2]; uint32_t u; } t;
  t.h[0] = (bf16_t)a; t.h[1] = (bf16_t)b;
  return t.u;
}

__device__ __forceinline__ float clampv(float v) {
  return fminf(fmaxf(v, -1.0e4f), 1.0e4f);
}

// Build one A/B fragment from transposed per-lane C-layout data (R5-verified).
// Source lane (qs,l16), block b: lo_b/hi_b = contraction-pairs qs*4+{0,1}/{2,3}.
// Dest lane (Q,l16) takes k-range Q*8..Q*8+7 from src lanes sA=(Q&1)*32+l16 and
// sB=sA+16, block selected by miHi=(Q>=2).
__device__ __forceinline__ bf16x8 quadshuf(uint32_t lo0, uint32_t hi0,
                                           uint32_t lo1, uint32_t hi1,
                                           int sA, int sB, bool miHi) {
  int a0 = __shfl((int)lo0, sA), a1 = __shfl((int)lo1, sA);
  int b0 = __shfl((int)hi0, sA), b1 = __shfl((int)hi1, sA);
  int c0 = __shfl((int)lo0, sB), c1 = __shfl((int)lo1, sB);
  int d0 = __shfl((int)hi0, sB), d1 = __shfl((int)hi1, sB);
  union { uint32_t w[4]; bf16x8 v; } f;
  f.w[0] = (uint32_t)(miHi ? a1 : a0);
  f.w[1] = (uint32_t)(miHi ? b1 : b0);
  f.w[2] = (uint32_t)(miHi ? c1 : c0);
  f.w[3] = (uint32_t)(miHi ? d1 : d0);
  return f.v;
}

// ---------------- merged prep: CPB-MLP bias table + fragment-major weights ----------
__global__ void prep_all(const float* __restrict__ Wq, const float* __restrict__ Wk,
                         const float* __restrict__ Wv, const float* __restrict__ Wo,
                         const float* __restrict__ w1, const float* __restrict__ b1,
                         const float* __restrict__ w2, bf16_t* __restrict__ wf,
                         float* __restrict__ tab, int doW) {
  if (blockIdx.x < 128) {
    if (!doW) return;
    int gid = blockIdx.x * 256 + threadIdx.x;  // 4 mats x 256 rows x 32 col-blocks
    int mat = gid >> 13, rem = gid & 8191;
    int row = rem >> 5, col = (rem & 31) << 3;
    const float* W = (mat == 0) ? Wq : (mat == 1) ? Wk : (mat == 2) ? Wv : Wo;
    bf16x8 v = cvt8(W + row * 256 + col);
    int rblk = row >> 4, kk = col >> 5, qd = (col >> 3) & 3, lr = row & 15;
    size_t dst = ((size_t)(((mat * 16 + rblk) * 8 + kk) * 64 + qd * 16 + lr)) * 8;
    *(bf16x8*)(wf + dst) = v;
    return;
  }
  if (threadIdx.x >= 64) return;
  int e = blockIdx.x - 128;  // 0..224
  int t = threadIdx.x;       // 0..63
  int a = e / 15, bcol = e % 15;
  float t0 = ((float)(a - 7) / 7.0f) * 8.0f;
  float t1 = ((float)(bcol - 7) / 7.0f) * 8.0f;
  float s0 = (t0 > 0.f) ? 1.f : ((t0 < 0.f) ? -1.f : 0.f);
  float s1 = (t1 > 0.f) ? 1.f : ((t1 < 0.f) ? -1.f : 0.f);
  t0 = s0 * log2f(fabsf(t0) + 1.f) * (1.0f / 3.0f);  // /log2(8)
  t1 = s1 * log2f(fabsf(t1) + 1.f) * (1.0f / 3.0f);
  float accv[8];
#pragma unroll
  for (int i = 0; i < 8; ++i) accv[i] = 0.f;
#pragma unroll
  for (int i = 0; i < 8; ++i) {
    int j = t + 64 * i;
    float hd = fmaxf(t0 * w1[2 * j] + t1 * w1[2 * j + 1] + b1[j], 0.f);
#pragma unroll
    for (int hh = 0; hh < 8; ++hh) accv[hh] += hd * w2[hh * 512 + j];
  }
#pragma unroll
  for (int hh = 0; hh < 8; ++hh) {
    float v = accv[hh];
    v += __shfl_xor(v, 1);  v += __shfl_xor(v, 2);  v += __shfl_xor(v, 4);
    v += __shfl_xor(v, 8);  v += __shfl_xor(v, 16); v += __shfl_xor(v, 32);
    accv[hh] = v;
  }
  if (t < 8) tab[e * 8 + t] = 16.f / (1.f + __expf(-accv[t]));
}

// ---------------- fused per-window attention ---------------------------------------
template <bool PREP>
__global__ void __launch_bounds__(512, 4) swin_fused(
    const float* __restrict__ x,
    const float* __restrict__ Wq, const float* __restrict__ bq,
    const float* __restrict__ Wk, const float* __restrict__ bk,
    const float* __restrict__ Wv, const float* __restrict__ bv,
    const float* __restrict__ Wo, const float* __restrict__ bo,
    const float* __restrict__ ls, const float* __restrict__ btab,
    const bf16_t* __restrict__ wf, float* __restrict__ out) {
  // 64 KB declared (32 KB used + pad) => exactly 2 blocks/CU: R4's streaming
  // pressure per XCD, but 16 waves/CU.
  __shared__ __align__(16) bf16_t xsf[32768];
  const int tid = threadIdx.x;
  const int lane = tid & 63, wave = tid >> 6, quad = lane >> 4, l16 = lane & 15;
  const int win = blockIdx.x, bb = win >> 6, wh = (win >> 3) & 7, ww = win & 7;
  const f32x4 fz = {0.f, 0.f, 0.f, 0.f};
  const int sA = ((quad & 1) << 5) | l16;  // quadshuf source lanes
  const int sB = sA + 16;
  const bool miHi = (lane & 32) != 0;
  const int h = wave;  // one head per wave

  // ---- Phase 0: stage shifted x-window -> xsf (fragment-major bf16) ----
  {
    int t = tid >> 3, f8 = tid & 7;  // token 0..63, 32-channel group 0..7
    int gh = (wh * 8 + (t >> 3) + 4) & 63;
    int gw = (ww * 8 + (t & 7) + 4) & 63;
    const float* xp = x + (size_t)((bb * 64 + gh) * 64 + gw) * 256 + f8 * 32;
#pragma unroll
    for (int fc = 0; fc < 4; ++fc)
      *(bf16x8*)(xsf + (f8 * 4 + fc) * 512 + t * 8) = cvt8(xp + fc * 8);
  }
  __syncthreads();

  // shifted-window mask region ids (R5-verified).
  // key m = KB*16 + quad*4 + r : m>>3 = KB*2+(quad>>1), m&7 = (quad&1)*4+r
  // query n = NB*16 + l16      : n>>3 = NB*2+(l16>>3),  n&7 = l16&7
  const bool lastr = (wh == 7), lastc = (ww == 7);
  int regm[4], regn[4];
#pragma unroll
  for (int b4 = 0; b4 < 4; ++b4) {
    regm[b4] = (lastr ? ((b4 * 2 + (quad >> 1)) < 4 ? 1 : 2) : 0) * 3 +
               (lastc ? ((quad & 1) ? 2 : 1) : 0);
    regn[b4] = (lastr ? ((b4 * 2 + (l16 >> 3)) < 4 ? 1 : 2) : 0) * 3 +
               (lastc ? (((l16 & 7) < 4) ? 1 : 2) : 0);
  }

  // ---- Phase A: projections. q,k SWAPPED (A=W -> out [dim][token]);
  //      v un-swapped (A=x -> out [token][dim]). ----
  f32x4 aq[2][4], ak[2][4], av[4][2];
#pragma unroll
  for (int mi = 0; mi < 2; ++mi)
#pragma unroll
    for (int nb = 0; nb < 4; ++nb) { aq[mi][nb] = fz; ak[mi][nb] = fz; }
#pragma unroll
  for (int mt = 0; mt < 4; ++mt) { av[mt][0] = fz; av[mt][1] = fz; }

#pragma unroll
  for (int kk = 0; kk < 8; ++kk) {
    bf16x8 af[4];
    const bf16_t* xb = xsf + ((kk * 4 + quad) * 64 + l16) * 8;
#pragma unroll
    for (int tb = 0; tb < 4; ++tb) af[tb] = *(const bf16x8*)(xb + tb * 128);
    bf16x8 wq_[2], wk_[2], wv_[2];
    if (PREP) {
      const bf16_t* wb = wf + (size_t)kk * 512 + (size_t)lane * 8;
#pragma unroll
      for (int mi = 0; mi < 2; ++mi) {
        wq_[mi] = *(const bf16x8*)(wb + (size_t)(h * 2 + mi) * 4096);
        wk_[mi] = *(const bf16x8*)(wb + (size_t)(16 + h * 2 + mi) * 4096);
        wv_[mi] = *(const bf16x8*)(wb + (size_t)(32 + h * 2 + mi) * 4096);
      }
    } else {
#pragma unroll
      for (int mi = 0; mi < 2; ++mi) {
        wq_[mi] = cvt8(Wq + (h * 32 + mi * 16 + l16) * 256 + kk * 32 + quad * 8);
        wk_[mi] = cvt8(Wk + (h * 32 + mi * 16 + l16) * 256 + kk * 32 + quad * 8);
        wv_[mi] = cvt8(Wv + (h * 32 + mi * 16 + l16) * 256 + kk * 32 + quad * 8);
      }
    }
#pragma unroll
    for (int mi = 0; mi < 2; ++mi)
#pragma unroll
      for (int tb = 0; tb < 4; ++tb) {
        aq[mi][tb] = mfma16(wq_[mi], af[tb], aq[mi][tb]);
        ak[mi][tb] = mfma16(wk_[mi], af[tb], ak[mi][tb]);
      }
#pragma unroll
    for (int mt = 0; mt < 4; ++mt)
#pragma unroll
      for (int nd = 0; nd < 2; ++nd)
        av[mt][nd] = mfma16(af[mt], wv_[nd], av[mt][nd]);
  }

  // ---- Phase B: bias + cosine-normalize (lane-local + 2 shfl), pack to bf16 ----
  float bqv[2][4], bkv[2][4];
#pragma unroll
  for (int mi = 0; mi < 2; ++mi)
#pragma unroll
    for (int r = 0; r < 4; ++r) {
      bqv[mi][r] = bq[h * 32 + mi * 16 + quad * 4 + r];
      bkv[mi][r] = bk[h * 32 + mi * 16 + quad * 4 + r];
    }
  const float bv0 = bv[h * 32 + l16], bv1 = bv[h * 32 + 16 + l16];

  uint32_t qlo[2][4], qhi[2][4], klo[2][4], khi[2][4];
#pragma unroll
  for (int nb = 0; nb < 4; ++nb) {
    float qv[2][4], kv[2][4];
    float sq = 0.f, sk = 0.f;
#pragma unroll
    for (int mi = 0; mi < 2; ++mi)
#pragma unroll
      for (int r = 0; r < 4; ++r) {
        float q0 = aq[mi][nb][r] + bqv[mi][r];
        float k0 = ak[mi][nb][r] + bkv[mi][r];
        qv[mi][r] = q0; kv[mi][r] = k0;
        sq += q0 * q0; sk += k0 * k0;
      }
    sq += __shfl_xor(sq, 16); sq += __shfl_xor(sq, 32);
    sk += __shfl_xor(sk, 16); sk += __shfl_xor(sk, 32);
    const float rq = 1.f / fmaxf(sqrtf(sq), 1e-12f);
    const float rk = 1.f / fmaxf(sqrtf(sk), 1e-12f);
#pragma unroll
    for (int mi = 0; mi < 2; ++mi) {
      qlo[mi][nb] = pack2(qv[mi][0] * rq, qv[mi][1] * rq);
      qhi[mi][nb] = pack2(qv[mi][2] * rq, qv[mi][3] * rq);
      klo[mi][nb] = pack2(kv[mi][0] * rk, kv[mi][1] * rk);
      khi[mi][nb] = pack2(kv[mi][2] * rk, kv[mi][3] * rk);
    }
  }
  uint32_t vlo[4][2], vhi[4][2];
#pragma unroll
  for (int mt = 0; mt < 4; ++mt)
#pragma unroll
    for (int nd = 0; nd < 2; ++nd) {
      const float bvb = nd ? bv1 : bv0;
      vlo[mt][nd] = pack2(av[mt][nd][0] + bvb, av[mt][nd][1] + bvb);
      vhi[mt][nd] = pack2(av[mt][nd][2] + bvb, av[mt][nd][3] + bvb);
    }

  // ---- Phase C: S^T = kn @ qn^T, fragments built in-register ----
  bf16x8 kfr[4], qfr[4];
#pragma unroll
  for (int tb = 0; tb < 4; ++tb)
    kfr[tb] = quadshuf(klo[0][tb], khi[0][tb], klo[1][tb], khi[1][tb], sA, sB, miHi);
#pragma unroll
  for (int tb = 0; tb < 4; ++tb)
    qfr[tb] = quadshuf(qlo[0][tb], qhi[0][tb], qlo[1][tb], qhi[1][tb], sA, sB, miHi);
  f32x4 s[4][4];  // s[KB][NB]: lane holds S[query NB*16+l16][key KB*16+quad*4+r]
#pragma unroll
  for (int KB = 0; KB < 4; ++KB)
#pragma unroll
    for (int NB = 0; NB < 4; ++NB) s[KB][NB] = mfma16(kfr[KB], qfr[NB], fz);

  const float scale = __expf(fminf(ls[h], 4.6051702f));  // exp(min(ls, ln 100))

  // ---- scale + CPB bias + shifted-window mask ----
#pragma unroll
  for (int KB = 0; KB < 4; ++KB) {
    const int mrow = KB * 2 + (quad >> 1);
    const int mcol0 = (quad & 1) * 4;
#pragma unroll
    for (int NB = 0; NB < 4; ++NB) {
      const int base = ((NB * 2 + (l16 >> 3)) - mrow + 7) * 15 +
                       ((l16 & 7) - mcol0 + 7);
      const bool msk = (regn[NB] != regm[KB]);
#pragma unroll
      for (int r = 0; r < 4; ++r) {
        float v = s[KB][NB][r] * scale + btab[(base - r) * 8 + h];
        if (msk) v -= 100.f;
        s[KB][NB][r] = v;
      }
    }
  }

  // ---- Phase D: softmax over keys (lane-local 16 + 2 shfl per query col) ----
  uint32_t plo[4][4], phi[4][4];
#pragma unroll
  for (int NB = 0; NB < 4; ++NB) {
    float mx = s[0][NB][0];
#pragma unroll
    for (int KB = 0; KB < 4; ++KB)
#pragma unroll
      for (int r = 0; r < 4; ++r) mx = fmaxf(mx, s[KB][NB][r]);
    mx = fmaxf(mx, __shfl_xor(mx, 16));
    mx = fmaxf(mx, __shfl_xor(mx, 32));
    float sum = 0.f;
#pragma unroll
    for (int KB = 0; KB < 4; ++KB)
#pragma unroll
      for (int r = 0; r < 4; ++r) {
        float p = __expf(s[KB][NB][r] - mx);
        s[KB][NB][r] = p;
        sum += p;
      }
    sum += __shfl_xor(sum, 16); sum += __shfl_xor(sum, 32);
    const float inv = 1.f / sum;
#pragma unroll
    for (int KB = 0; KB < 4; ++KB) {
      plo[KB][NB] = pack2(s[KB][NB][0] * inv, s[KB][NB][1] * inv);
      phi[KB][NB] = pack2(s[KB][NB][2] * inv, s[KB][NB][3] * inv);
    }
  }

  // ---- Phase E: O^T = V^T @ P (fragments in-register, 2 K-steps of 32 keys) ----
  f32x4 oh[2][4];  // [dim-block][query-block]
#pragma unroll
  for (int DB = 0; DB < 2; ++DB)
#pragma unroll
    for (int NB = 0; NB < 4; ++NB) oh[DB][NB] = fz;
#pragma unroll
  for (int st = 0; st < 2; ++st) {
    bf16x8 vfr[2], pfr[4];
#pragma unroll
    for (int DB = 0; DB < 2; ++DB)
      vfr[DB] = quadshuf(vlo[2 * st][DB], vhi[2 * st][DB],
                         vlo[2 * st + 1][DB], vhi[2 * st + 1][DB], sA, sB, miHi);
#pragma unroll
    for (int NB = 0; NB < 4; ++NB)
      pfr[NB] = quadshuf(plo[2 * st][NB], phi[2 * st][NB],
                         plo[2 * st + 1][NB], phi[2 * st + 1][NB], sA, sB, miHi);
#pragma unroll
    for (int DB = 0; DB < 2; ++DB)
#pragma unroll
      for (int NB = 0; NB < 4; ++NB)
        oh[DB][NB] = mfma16(vfr[DB], pfr[NB], oh[DB][NB]);
  }

  // all waves past their Phase-A xsf reads here; overlay y frags on xsf.
  __syncthreads();
  // write O^T into y frags: channel f = h*32 + DB*16 + quad*4 + r, token nb*16+l16
#pragma unroll
  for (int DB = 0; DB < 2; ++DB)
#pragma unroll
    for (int nb = 0; nb < 4; ++nb)
#pragma unroll
      for (int r = 0; r < 4; ++r)
        xsf[(h * 4 + DB * 2 + (quad >> 1)) * 512 + (nb * 16 + l16) * 8 +
            ((quad & 1) << 2) + r] = (bf16_t)oh[DB][nb][r];
  __syncthreads();

  // ---- Phase F: out = y @ Wo^T + bo (wave covers 32 out channels) ----
  f32x4 a2[4][2];
#pragma unroll
  for (int mi = 0; mi < 4; ++mi) { a2[mi][0] = fz; a2[mi][1] = fz; }

#pragma unroll
  for (int kk = 0; kk < 8; ++kk) {
    bf16x8 af[4];
    const bf16_t* yb = xsf + ((kk * 4 + quad) * 64 + l16) * 8;
#pragma unroll
    for (int mi = 0; mi < 4; ++mi) af[mi] = *(const bf16x8*)(yb + mi * 128);
#pragma unroll
    for (int ni = 0; ni < 2; ++ni) {
      bf16x8 bw;
      if (PREP)
        bw = *(const bf16x8*)(wf + (size_t)(((48 + wave * 2 + ni) * 8 + kk) * 64 + lane) * 8);
      else
        bw = cvt8(Wo + (wave * 32 + ni * 16 + l16) * 256 + kk * 32 + quad * 8);
#pragma unroll
      for (int mi = 0; mi < 4; ++mi) a2[mi][ni] = mfma16(af[mi], bw, a2[mi][ni]);
    }
  }

  const float bor0 = bo[wave * 32 + l16], bor1 = bo[wave * 32 + 16 + l16];
#pragma unroll
  for (int mi = 0; mi < 4; ++mi)
#pragma unroll
    for (int r = 0; r < 4; ++r) {
      int row = mi * 16 + quad * 4 + r;
      int gh = (wh * 8 + (row >> 3) + 4) & 63;
      int gw = (ww * 8 + (row & 7) + 4) & 63;
      float* op = out + (size_t)((bb * 64 + gh) * 64 + gw) * 256 + wave * 32 + l16;
      op[0]  = clampv(a2[mi][0][r] + bor0);
      op[16] = clampv(a2[mi][1][r] + bor1);
    }
}

extern "C" void kernel_launch(void* const* d_in, const int* in_sizes, int n_in,
                              void* d_out, int out_size, void* d_ws, size_t ws_size,
                              hipStream_t stream) {
  const float* x  = (const float*)d_in[0];
  const float* Wq = (const float*)d_in[1];
  const float* bq = (const float*)d_in[2];
  const float* Wk = (const float*)d_in[3];
  const float* bk = (const float*)d_in[4];
  const float* Wv = (const float*)d_in[5];
  const float* bv = (const float*)d_in[6];
  const float* Wo = (const float*)d_in[7];
  const float* bo = (const float*)d_in[8];
  const float* ls = (const float*)d_in[9];
  const float* w1 = (const float*)d_in[10];
  const float* b1 = (const float*)d_in[11];
  const float* w2 = (const float*)d_in[12];

  float* tab = (float*)d_ws;                           // 1800 floats (7.2 KB)
  bf16_t* wfrag = (bf16_t*)((char*)d_ws + 7680);       // 512 KB fragment-major weights
  const bool prep = ws_size >= (size_t)(7680 + 524288);  // constant across calls

  hipLaunchKernelGGL(prep_all, dim3(353), dim3(256), 0, stream,
                     Wq, Wk, Wv, Wo, w1, b1, w2, wfrag, tab, prep ? 1 : 0);
  if (prep) {
    hipLaunchKernelGGL((swin_fused<true>), dim3(2048), dim3(512), 0, stream,
                       x, Wq, bq, Wk, bk, Wv, bv, Wo, bo, ls, tab, wfrag, (float*)d_out);
  } else {
    hipLaunchKernelGGL((swin_fused<false>), dim3(2048), dim3(512), 0, stream,
                       x, Wq, bq, Wk, bk, Wv, bv, Wo, bo, ls, tab, wfrag, (float*)d_out);
  }
}